// Round 3
// baseline (435.428 us; speedup 1.0000x reference)
//
#include <hip/hip_runtime.h>
#include <math.h>

#define WAVE 64
#define NH 50    // 2*(L+1)^2 for L=4
#define HALF 32  // points per transpose phase
#define GRID 4096  // persistent: ~16 single-wave blocks/CU on 256 CUs

typedef float f32x4 __attribute__((ext_vector_type(4)));  // clang vector: OK for nontemporal builtins

// Normalization constants N(l,m) = sqrt((2l+1)/(4pi) * (l-m)!/(l+m)!)
#define N00 0.28209479177387814f
#define N10 0.4886025119029199f
#define N11 0.34549414947133547f
#define N20 0.6307831305050401f
#define N21 0.2575161346821977f
#define N22 0.12875806734109884f
#define N30 0.7463526651802308f
#define N31 0.2154534560761004f
#define N32 0.06813236509610091f
#define N33 0.02781492157551894f
#define N40 0.8462843753216345f
#define N41 0.18923493915151202f
#define N42 0.04460301380579704f
#define N43 0.011920680675223072f
#define N44 0.004214597070904597f

// PERSISTENT single-wave workgroups + software pipelining:
// Round-1 falsified the occupancy theory (12->16 blocks/CU: flat). The fill
// kernel calibrates the store path at 6.2 TB/s with the SAME coalesced-x4
// pattern, so the remaining gap is the serial per-workgroup dependency chain
// (load ~900cy -> compute -> LDS -> stores -> retire) with no intra-wave
// overlap. Fix: each block owns 8 contiguous 64-pt chunks and PREFETCHES the
// next chunk's xyz before computing the current one — HBM load latency hides
// under ~1000cy of compute+store issue; launch/drain amortized 8x.
__global__ __launch_bounds__(WAVE) void sh_embed_kernel(
    const float* __restrict__ dirs, float* __restrict__ out, int npts,
    int nchunks, int cpb) {
    __shared__ float lds[HALF * NH];  // 6.4 KB

    const int lane = threadIdx.x;
    const int c0 = blockIdx.x * cpb;
    if (c0 >= nchunks) return;
    const int c1 = (c0 + cpb < nchunks) ? (c0 + cpb) : nchunks;

    // Prefetch chunk c0
    float x = 0.f, y = 0.f, z = 0.f;
    {
        int pt = c0 * WAVE + lane;
        if (pt < npts) {
            const float* p = dirs + (size_t)pt * 3;
            x = p[0]; y = p[1]; z = p[2];
        }
    }

    for (int c = c0; c < c1; ++c) {
        const int base_pt = c * WAVE;

        // Issue next chunk's load NOW; first use is next iteration, so its
        // ~900cy latency hides under this chunk's compute + transpose + stores.
        float nx = 0.f, ny = 0.f, nz = 0.f;
        if (c + 1 < c1) {
            int npt = (c + 1) * WAVE + lane;
            if (npt < npts) {
                const float* p = dirs + (size_t)npt * 3;
                nx = p[0]; ny = p[1]; nz = p[2];
            }
        }

        // cos(theta), sin(theta) exactly as reference
        float ct = fminf(fmaxf(z, -1.f), 1.f);
        float st2 = fminf(fmaxf(1.f - ct * ct, 0.f), 1.f);
        float st = sqrtf(st2);

        // cos(phi), sin(phi) without atan2: phi = atan2(y, x)
        float rxy2 = x * x + y * y;
        float c1p, s1;
        if (rxy2 > 0.f) {
            float inv = rsqrtf(rxy2);
            c1p = x * inv;
            s1 = y * inv;
        } else {
            c1p = 1.f;  // atan2(0,0) = 0
            s1 = 0.f;
        }
        // Chebyshev multiples
        float c2 = c1p * c1p - s1 * s1;
        float s2 = 2.f * c1p * s1;
        float c3 = c2 * c1p - s2 * s1;
        float s3 = s2 * c1p + c2 * s1;
        float c4 = c3 * c1p - s3 * s1;
        float s4 = s3 * c1p + c3 * s1;

        // Associated Legendre, L=4, Condon-Shortley phase (matches reference)
        float P10 = ct;
        float P11 = -st;
        float P20 = 1.5f * ct * ct - 0.5f;
        float P21 = -3.f * ct * st;
        float P22 = 3.f * st2;
        float P30 = (5.f * ct * P20 - 2.f * P10) * (1.f / 3.f);
        float P31 = (5.f * ct * P21 - 3.f * P11) * 0.5f;
        float P32 = 15.f * ct * st2;
        float P33 = -15.f * st2 * st;
        float P40 = (7.f * ct * P30 - 3.f * P20) * 0.25f;
        float P41 = (7.f * ct * P31 - 4.f * P21) * (1.f / 3.f);
        float P42 = (7.f * ct * P32 - 5.f * P22) * 0.5f;
        float P43 = -105.f * ct * st2 * st;
        float P44 = 105.f * st2 * st2;

        float v[NH];
        // l=0
        v[0] = N00;
        v[1] = 0.f;
        // l=1
        {
            float B = N11 * P11;
            float r = B * c1p, i = B * s1;
            v[2] = -r; v[3] = i;        // m=-1: s=(-1)^1=-1 -> (-r, +i)
            v[4] = N10 * P10; v[5] = 0.f;
            v[6] = r; v[7] = i;
        }
        // l=2
        {
            float B2 = N22 * P22, B1 = N21 * P21;
            float r2 = B2 * c2, i2 = B2 * s2;
            float r1 = B1 * c1p, i1 = B1 * s1;
            v[8] = r2;  v[9] = -i2;     // m=-2: s=+1 -> (r, -i)
            v[10] = -r1; v[11] = i1;    // m=-1
            v[12] = N20 * P20; v[13] = 0.f;
            v[14] = r1; v[15] = i1;
            v[16] = r2; v[17] = i2;
        }
        // l=3
        {
            float B3 = N33 * P33, B2 = N32 * P32, B1 = N31 * P31;
            float r3 = B3 * c3, i3 = B3 * s3;
            float r2 = B2 * c2, i2 = B2 * s2;
            float r1 = B1 * c1p, i1 = B1 * s1;
            v[18] = -r3; v[19] = i3;    // m=-3: s=-1
            v[20] = r2;  v[21] = -i2;   // m=-2: s=+1
            v[22] = -r1; v[23] = i1;    // m=-1
            v[24] = N30 * P30; v[25] = 0.f;
            v[26] = r1; v[27] = i1;
            v[28] = r2; v[29] = i2;
            v[30] = r3; v[31] = i3;
        }
        // l=4
        {
            float B4 = N44 * P44, B3 = N43 * P43, B2 = N42 * P42, B1 = N41 * P41;
            float r4 = B4 * c4, i4 = B4 * s4;
            float r3 = B3 * c3, i3 = B3 * s3;
            float r2 = B2 * c2, i2 = B2 * s2;
            float r1 = B1 * c1p, i1 = B1 * s1;
            v[32] = r4;  v[33] = -i4;   // m=-4: s=+1
            v[34] = -r3; v[35] = i3;    // m=-3: s=-1
            v[36] = r2;  v[37] = -i2;   // m=-2
            v[38] = -r1; v[39] = i1;    // m=-1
            v[40] = N40 * P40; v[41] = 0.f;
            v[42] = r1; v[43] = i1;
            v[44] = r2; v[45] = i2;
            v[46] = r3; v[47] = i3;
            v[48] = r4; v[49] = i4;
        }

        const int valid = npts - base_pt;  // may exceed WAVE; clamped per phase

        // ---------- phase 0: points [base_pt, base_pt+32) ----------
        // 32 lanes over 16 banks = 2-way aliasing (free, m136)
        if (lane < HALF) {
            float2* row = (float2*)&lds[lane * NH];
#pragma unroll
            for (int k = 0; k < NH / 2; ++k) {
                row[k] = make_float2(v[2 * k], v[2 * k + 1]);
            }
        }
        __syncthreads();

        if (valid >= HALF) {
            // 32 pts * 50 floats = 400 f32x4; 6 full rounds of 64 + 16 tail
            const f32x4* lds4 = (const f32x4*)lds;
            f32x4* out4 = (f32x4*)(out + (size_t)base_pt * NH);
#pragma unroll
            for (int k = 0; k < 6; ++k) {
                __builtin_nontemporal_store(lds4[k * WAVE + lane], &out4[k * WAVE + lane]);
            }
            if (lane < 16) {
                __builtin_nontemporal_store(lds4[6 * WAVE + lane], &out4[6 * WAVE + lane]);
            }
        } else if (valid > 0) {
            float* outp = out + (size_t)base_pt * NH;
            int n = valid * NH;
            for (int i = lane; i < n; i += WAVE) {
                outp[i] = lds[i];
            }
        }
        __syncthreads();  // WAR: phase-1 staging overwrites the buffer

        // ---------- phase 1: points [base_pt+32, base_pt+64) ----------
        if (lane >= HALF) {
            float2* row = (float2*)&lds[(lane - HALF) * NH];
#pragma unroll
            for (int k = 0; k < NH / 2; ++k) {
                row[k] = make_float2(v[2 * k], v[2 * k + 1]);
            }
        }
        __syncthreads();

        const int valid1 = valid - HALF;
        if (valid1 >= HALF) {
            const f32x4* lds4 = (const f32x4*)lds;
            f32x4* out4 = (f32x4*)(out + (size_t)(base_pt + HALF) * NH);
#pragma unroll
            for (int k = 0; k < 6; ++k) {
                __builtin_nontemporal_store(lds4[k * WAVE + lane], &out4[k * WAVE + lane]);
            }
            if (lane < 16) {
                __builtin_nontemporal_store(lds4[6 * WAVE + lane], &out4[6 * WAVE + lane]);
            }
        } else if (valid1 > 0) {
            float* outp = out + (size_t)(base_pt + HALF) * NH;
            int n = valid1 * NH;
            for (int i = lane; i < n; i += WAVE) {
                outp[i] = lds[i];
            }
        }
        __syncthreads();  // WAR: next iteration's phase-0 staging reuses lds

        x = nx; y = ny; z = nz;
    }
}

extern "C" void kernel_launch(void* const* d_in, const int* in_sizes, int n_in,
                              void* d_out, int out_size, void* d_ws, size_t ws_size,
                              hipStream_t stream) {
    const float* dirs = (const float*)d_in[0];
    float* out = (float*)d_out;
    int npts = in_sizes[0] / 3;
    int nchunks = (npts + WAVE - 1) / WAVE;
    int grid = (nchunks < GRID) ? nchunks : GRID;
    int cpb = (nchunks + grid - 1) / grid;  // =8 at npts=2M
    sh_embed_kernel<<<dim3(grid), dim3(WAVE), 0, stream>>>(dirs, out, npts, nchunks, cpb);
}

// Round 4
// 419.491 us; speedup vs baseline: 1.0380x; 1.0380x over previous
//
#include <hip/hip_runtime.h>
#include <math.h>

#define WAVE 64
#define NH 50  // 2*(L+1)^2 for L=4

typedef float f32x4 __attribute__((ext_vector_type(4)));

// Normalization constants N(l,m) = sqrt((2l+1)/(4pi) * (l-m)!/(l+m)!)
#define N00 0.28209479177387814f
#define N10 0.4886025119029199f
#define N11 0.34549414947133547f
#define N20 0.6307831305050401f
#define N21 0.2575161346821977f
#define N22 0.12875806734109884f
#define N30 0.7463526651802308f
#define N31 0.2154534560761004f
#define N32 0.06813236509610091f
#define N33 0.02781492157551894f
#define N40 0.8462843753216345f
#define N41 0.18923493915151202f
#define N42 0.04460301380579704f
#define N43 0.011920680675223072f
#define N44 0.004214597070904597f

// R4: exact R0 structure (best measured: 419.3 us) with ONE change:
// plain stores instead of __builtin_nontemporal_store. The rocclr fill
// kernel sustains 6.2 TB/s with plain dwordx4 stores; our nt-flagged
// stream runs at ~2.8 TB/s effective with every other pipe (VALU/LDS/
// TRANS/occupancy) accounted for and exonerated by R1/R2 null results.
// A/B target: the nt bit itself.
__global__ __launch_bounds__(WAVE) void sh_embed_kernel(
    const float* __restrict__ dirs, float* __restrict__ out, int npts) {
    __shared__ float lds[WAVE * NH];  // 12.8 KB

    const int lane = threadIdx.x;
    const int base_pt = blockIdx.x * WAVE;
    const int pt = base_pt + lane;

    float x = 0.f, y = 0.f, z = 0.f;
    if (pt < npts) {
        const float* p = dirs + (size_t)pt * 3;
        x = p[0];
        y = p[1];
        z = p[2];
    }

    // cos(theta), sin(theta) exactly as reference
    float ct = fminf(fmaxf(z, -1.f), 1.f);
    float st2 = fminf(fmaxf(1.f - ct * ct, 0.f), 1.f);
    float st = sqrtf(st2);

    // cos(phi), sin(phi) without atan2: phi = atan2(y, x)
    float rxy2 = x * x + y * y;
    float c1, s1;
    if (rxy2 > 0.f) {
        float inv = rsqrtf(rxy2);
        c1 = x * inv;
        s1 = y * inv;
    } else {
        c1 = 1.f;  // atan2(0,0) = 0
        s1 = 0.f;
    }
    // Chebyshev multiples
    float c2 = c1 * c1 - s1 * s1;
    float s2 = 2.f * c1 * s1;
    float c3 = c2 * c1 - s2 * s1;
    float s3 = s2 * c1 + c2 * s1;
    float c4 = c3 * c1 - s3 * s1;
    float s4 = s3 * c1 + c3 * s1;

    // Associated Legendre, L=4, Condon-Shortley phase (matches reference recurrences)
    float P10 = ct;
    float P11 = -st;
    float P20 = 1.5f * ct * ct - 0.5f;
    float P21 = -3.f * ct * st;
    float P22 = 3.f * st2;
    float P30 = (5.f * ct * P20 - 2.f * P10) * (1.f / 3.f);
    float P31 = (5.f * ct * P21 - 3.f * P11) * 0.5f;
    float P32 = 15.f * ct * st2;
    float P33 = -15.f * st2 * st;
    float P40 = (7.f * ct * P30 - 3.f * P20) * 0.25f;
    float P41 = (7.f * ct * P31 - 4.f * P21) * (1.f / 3.f);
    float P42 = (7.f * ct * P32 - 5.f * P22) * 0.5f;
    float P43 = -105.f * ct * st2 * st;
    float P44 = 105.f * st2 * st2;

    float v[NH];
    // l=0
    v[0] = N00;
    v[1] = 0.f;
    // l=1
    {
        float B = N11 * P11;
        float r = B * c1, i = B * s1;
        v[2] = -r; v[3] = i;        // m=-1: s=(-1)^1=-1 -> (-r, +i)
        v[4] = N10 * P10; v[5] = 0.f;
        v[6] = r; v[7] = i;
    }
    // l=2
    {
        float B2 = N22 * P22, B1 = N21 * P21;
        float r2 = B2 * c2, i2 = B2 * s2;
        float r1 = B1 * c1, i1 = B1 * s1;
        v[8] = r2;  v[9] = -i2;     // m=-2: s=+1 -> (r, -i)
        v[10] = -r1; v[11] = i1;    // m=-1
        v[12] = N20 * P20; v[13] = 0.f;
        v[14] = r1; v[15] = i1;
        v[16] = r2; v[17] = i2;
    }
    // l=3
    {
        float B3 = N33 * P33, B2 = N32 * P32, B1 = N31 * P31;
        float r3 = B3 * c3, i3 = B3 * s3;
        float r2 = B2 * c2, i2 = B2 * s2;
        float r1 = B1 * c1, i1 = B1 * s1;
        v[18] = -r3; v[19] = i3;    // m=-3: s=-1
        v[20] = r2;  v[21] = -i2;   // m=-2: s=+1
        v[22] = -r1; v[23] = i1;    // m=-1
        v[24] = N30 * P30; v[25] = 0.f;
        v[26] = r1; v[27] = i1;
        v[28] = r2; v[29] = i2;
        v[30] = r3; v[31] = i3;
    }
    // l=4
    {
        float B4 = N44 * P44, B3 = N43 * P43, B2 = N42 * P42, B1 = N41 * P41;
        float r4 = B4 * c4, i4 = B4 * s4;
        float r3 = B3 * c3, i3 = B3 * s3;
        float r2 = B2 * c2, i2 = B2 * s2;
        float r1 = B1 * c1, i1 = B1 * s1;
        v[32] = r4;  v[33] = -i4;   // m=-4: s=+1
        v[34] = -r3; v[35] = i3;    // m=-3: s=-1
        v[36] = r2;  v[37] = -i2;   // m=-2
        v[38] = -r1; v[39] = i1;    // m=-1
        v[40] = N40 * P40; v[41] = 0.f;
        v[42] = r1; v[43] = i1;
        v[44] = r2; v[45] = i2;
        v[46] = r3; v[47] = i3;
        v[48] = r4; v[49] = i4;
    }

    // Stage to LDS (row layout; stride 50 dwords -> 4-way write conflict, accepted)
    {
        float2* row = (float2*)&lds[lane * NH];
#pragma unroll
        for (int k = 0; k < NH / 2; ++k) {
            row[k] = make_float2(v[2 * k], v[2 * k + 1]);
        }
    }
    __syncthreads();  // single-wave block: compiler waitcnt + near-free barrier

    // Coalesced writeback: 64*50 floats = 800 float4, 12.5/lane — PLAIN stores
    int valid_pts = npts - base_pt;
    if (valid_pts >= WAVE) {
        const f32x4* lds4 = (const f32x4*)lds;
        f32x4* out4 = (f32x4*)(out + (size_t)base_pt * NH);
#pragma unroll
        for (int k = 0; k < 12; ++k) {
            out4[k * WAVE + lane] = lds4[k * WAVE + lane];
        }
        if (lane < 32) {
            out4[12 * WAVE + lane] = lds4[12 * WAVE + lane];
        }
    } else if (valid_pts > 0) {
        float* outp = out + (size_t)base_pt * NH;
        int n = valid_pts * NH;
        for (int i = lane; i < n; i += WAVE) {
            outp[i] = lds[i];
        }
    }
}

extern "C" void kernel_launch(void* const* d_in, const int* in_sizes, int n_in,
                              void* d_out, int out_size, void* d_ws, size_t ws_size,
                              hipStream_t stream) {
    const float* dirs = (const float*)d_in[0];
    float* out = (float*)d_out;
    int npts = in_sizes[0] / 3;
    int nblocks = (npts + WAVE - 1) / WAVE;
    sh_embed_kernel<<<dim3(nblocks), dim3(WAVE), 0, stream>>>(dirs, out, npts);
}